// Round 5
// baseline (204.558 us; speedup 1.0000x reference)
//
#include <hip/hip_runtime.h>
#include <stdint.h>

// Problem constants
#define BB 4
#define CC 256
#define HH 96
#define WW 96
#define HP 98      // halo-padded spatial dim
#define CP 264     // k-stride per x in ush (528 B; measured ~conflict-free b128 frags)
#define XT 32      // x positions per block
#define XE 34      // staged x entries (32 + 2 halo)

typedef __bf16 bf16x8 __attribute__((ext_vector_type(8)));
typedef float f32x4 __attribute__((ext_vector_type(4)));
typedef float f32x16 __attribute__((ext_vector_type(16)));

__device__ __forceinline__ uint16_t f2bf(float f) {
    uint32_t u = __float_as_uint(f);
    u += 0x7FFFu + ((u >> 16) & 1u);   // round-to-nearest-even
    return (uint16_t)(u >> 16);
}

// ---------------------------------------------------------------------------
// Pre-kernel 1: cen (NCHW fp32) -> cenT [b][hy 98][hx 98][264] bf16 (halo=0 via
// prior memset). Block = (y, b, c-half): 25.6 KB LDS.
// ---------------------------------------------------------------------------
__global__ void transpose_cen(const float* __restrict__ cen, uint16_t* __restrict__ cenT) {
    const int y = blockIdx.x, b = blockIdx.y, ch = blockIdx.z, tid = threadIdx.x;
    __shared__ uint16_t ldsX[128 * 100];

    #pragma unroll
    for (int i = 0; i < 12; ++i) {
        int f = i * 256 + tid;            // 0..3071: 128 c x 24 xq
        int c = f / 24, xq = f % 24;
        float4 v = *(const float4*)(cen + ((((size_t)b * CC + ch * 128 + c) * HH + y) * WW + xq * 4));
        uint2 pk;
        pk.x = (uint32_t)f2bf(v.x) | ((uint32_t)f2bf(v.y) << 16);
        pk.y = (uint32_t)f2bf(v.z) | ((uint32_t)f2bf(v.w) << 16);
        *(uint2*)(&ldsX[c * 100 + xq * 4]) = pk;
    }
    __syncthreads();
    #pragma unroll
    for (int i = 0; i < 6; ++i) {
        int t = i * 256 + tid;            // 0..1535: 96 x * 16 cq
        int x = t % 96, cq = t / 96;
        uint32_t w0, w1, w2, w3;
        w0 = (uint32_t)ldsX[(cq * 8 + 0) * 100 + x] | ((uint32_t)ldsX[(cq * 8 + 1) * 100 + x] << 16);
        w1 = (uint32_t)ldsX[(cq * 8 + 2) * 100 + x] | ((uint32_t)ldsX[(cq * 8 + 3) * 100 + x] << 16);
        w2 = (uint32_t)ldsX[(cq * 8 + 4) * 100 + x] | ((uint32_t)ldsX[(cq * 8 + 5) * 100 + x] << 16);
        w3 = (uint32_t)ldsX[(cq * 8 + 6) * 100 + x] | ((uint32_t)ldsX[(cq * 8 + 7) * 100 + x] << 16);
        size_t o = (((size_t)b * HP + (y + 1)) * HP + (x + 1)) * CP + ch * 128 + cq * 8;
        *(uint4*)(cenT + o) = make_uint4(w0, w1, w2, w3);
    }
}

// ---------------------------------------------------------------------------
// Pre-kernel 2: W3 [9][256 n][256 k] fp32 -> W3bf [g][t 8][ks 16][m 32][kh 2][8]
// A-frag (32x32x16: lane m holds k = kh*8 + j) for (g,t,ks) = 1 KiB contiguous.
// ---------------------------------------------------------------------------
__global__ void cvt_w3(const float* __restrict__ W3, uint16_t* __restrict__ W3bf) {
    int e = (blockIdx.x * 256 + threadIdx.x) * 4;   // 0..589823
    int g = e >> 16, n = (e >> 8) & 255, k = e & 255;
    float4 v = *(const float4*)(W3 + e);
    uint2 pk;
    pk.x = (uint32_t)f2bf(v.x) | ((uint32_t)f2bf(v.y) << 16);
    pk.y = (uint32_t)f2bf(v.z) | ((uint32_t)f2bf(v.w) << 16);
    size_t o = (size_t)(((g * 8 + (n >> 5)) * 16 + (k >> 4)) * 512)
             + (n & 31) * 16 + ((k >> 3) & 1) * 8 + (k & 7);
    *(uint2*)(W3bf + o) = pk;
}

// ---------------------------------------------------------------------------
// Main kernel: grid (3 xt, 96 y, 4 b) = 1152 blocks, 512 thr (8 waves).
// Block tile: 32 positions (1 row) x 256 ch; wave w = ch-tile w (32 ch).
// Wave footprint halved vs R4: ONE acc + ONE fin (32 AGPR) + lean arch
// -> alloc <= 85 -> 6 waves/SIMD = 3 blocks/CU = 24 waves/CU for latency
// hiding; 4.5 blocks/CU pipelined 3-deep kills the 2-phase tail.
// mfma_f32_32x32x16_bf16, D[ch][pos]; A = W3 frag (global/L2/L1);
// B = shifted-cen frag from a single rolling LDS row (17.9 KB).
// ---------------------------------------------------------------------------
__global__ __launch_bounds__(512, 6)
void ecm_main(const float* __restrict__ cen, const uint16_t* __restrict__ cenT,
              const uint16_t* __restrict__ W3bf, float* __restrict__ out) {
    const int tid = threadIdx.x;
    const int wv = tid >> 6, lane = tid & 63, col = lane & 31, kh = lane >> 5;
    const int x0 = blockIdx.x * XT, y = blockIdx.y, b = blockIdx.z;

    __shared__ __align__(16) uint16_t ldsA[XE * CP];   // 17,952 B (one cenT row)
    __shared__ __align__(16) float ldsP[2][32][8];     // ping-pong norm partials (2 KB)

    // g processed in dy-groups; dgOrd[idx] = reference g index, dx = idx%3 - 1.
    const int dgOrd[9] = {0, 1, 2, 7, 8, 3, 6, 5, 4};

    const uint16_t* wbase = W3bf + (size_t)wv * (16 * 512) + col * 16 + kh * 8;
    const int abase = col * CP + kh * 8;

    f32x16 fin = {};

    #pragma unroll 1
    for (int idx = 0; idx < 9; ++idx) {
        const int g = dgOrd[idx], dg = idx / 3, dx = idx % 3 - 1;

        if (idx % 3 == 0) {
            // Restage input row (y-1+dg) = cenT row (y+dg). Safe: all ldsA
            // reads of the previous g precede its norm barrier.
            const uint4* gs = (const uint4*)(cenT + (((size_t)b * HP + (y + dg)) * HP + x0) * CP);
            uint4* ls = (uint4*)ldsA;
            for (int c = tid; c < XE * CP / 8; c += 512) ls[c] = gs[c];
            __syncthreads();
        }

        const uint16_t* wg = wbase + (size_t)g * (8 * 16 * 512);
        const int a = abase + (dx + 1) * CP;

        f32x16 acc = {};
        #pragma unroll 2
        for (int ks = 0; ks < 16; ++ks) {
            bf16x8 wf = *(const bf16x8*)(wg + ks * 512);           // 1 KB coalesced, L1/L2
            bf16x8 bf = *(const bf16x8*)(ldsA + a + ks * 16);      // ds_read_b128
            acc = __builtin_amdgcn_mfma_f32_32x32x16_bf16(wf, bf, acc, 0, 0, 0);
        }

        // Per-position ||Y||^2 partial over this wave's 32 ch (col = position).
        float s = 0.f;
        #pragma unroll
        for (int r = 0; r < 16; ++r) s += acc[r] * acc[r];
        s += __shfl_xor(s, 32, 64);
        if (kh == 0) ldsP[idx & 1][col][wv] = s;
        __syncthreads();   // the ONLY per-g barrier (ping-pong covers WAR)

        f32x4 pa = *(const f32x4*)&ldsP[idx & 1][col][0];
        f32x4 pb = *(const f32x4*)&ldsP[idx & 1][col][4];
        float n = pa[0] + pa[1] + pa[2] + pa[3] + pb[0] + pb[1] + pb[2] + pb[3];
        const float sgn = (g == 8) ? 1.f : -1.f;
        float sc = sgn / fmaxf(sqrtf(n), 1e-12f);
        #pragma unroll
        for (int r = 0; r < 16; ++r) fin[r] += acc[r] * sc;
    }

    // Epilogue: out = fin + cen. D row->ch: (reg&3) + 8*(reg>>2) + 4*kh (+32*wv).
    #pragma unroll
    for (int r = 0; r < 16; ++r) {
        int ch = wv * 32 + (r & 3) + 8 * (r >> 2) + 4 * kh;
        size_t o = (((size_t)b * CC + ch) * HH + y) * WW + (x0 + col);
        out[o] = fin[r] + cen[o];
    }
}

extern "C" void kernel_launch(void* const* d_in, const int* in_sizes, int n_in,
                              void* d_out, int out_size, void* d_ws, size_t ws_size,
                              hipStream_t stream) {
    const float* cen = (const float*)d_in[0];
    // d_in[1] = W1, d_in[2] = W2: dead code (softmax over size-1 axis == 1.0)
    const float* W3 = (const float*)d_in[3];
    float* out = (float*)d_out;

    uint16_t* cenT = (uint16_t*)d_ws;                         // [4][98][98][264] bf16
    const size_t cenT_elems = (size_t)BB * HP * HP * CP;
    uint16_t* W3bf = cenT + cenT_elems;                       // [9][8][16][512] bf16

    hipMemsetAsync(d_ws, 0, cenT_elems * sizeof(uint16_t), stream);   // zero halos
    transpose_cen<<<dim3(HH, BB, 2), 256, 0, stream>>>(cen, cenT);
    cvt_w3<<<576, 256, 0, stream>>>(W3, W3bf);
    ecm_main<<<dim3(3, HH, BB), 512, 0, stream>>>(cen, cenT, W3bf, out);
}